// Round 1
// 461.511 us; speedup vs baseline: 1.2914x; 1.2914x over previous
//
#include <hip/hip_runtime.h>
#include <cstdint>

typedef unsigned short u16;
typedef __attribute__((ext_vector_type(8))) short short8;
typedef __attribute__((ext_vector_type(8))) unsigned short ushort8;
typedef __attribute__((ext_vector_type(4))) float floatx4;
typedef __attribute__((ext_vector_type(4))) _Float16 half4;

#define S_LEN 1024
#define BATCH 64
#define EDIM 1024
#define UDIM 1024
#define VOCAB 32000
#define NTOT (3 * UDIM)        // 3072
#define CT 64                  // timesteps per scan chunk
#define NC (S_LEN / CT)        // 16 chunks

__device__ __forceinline__ u16 f2bf(float x) {
  unsigned u = __float_as_uint(x);
  return (u16)((u + 0x7fffu + ((u >> 16) & 1u)) >> 16);  // RNE, inputs are finite
}

// async global->LDS, 16B per lane. LDS dest must be wave-uniform base + lane*16.
__device__ __forceinline__ void async16(const u16* g, u16* s) {
  __builtin_amdgcn_global_load_lds(
      (__attribute__((address_space(1))) void*)(uintptr_t)g,
      (__attribute__((address_space(3))) void*)(uintptr_t)s,
      16, 0, 0);
}

__device__ __forceinline__ float sigm(float x) {
  return __builtin_amdgcn_rcpf(1.f + __expf(-x));
}

// ---------------- convert emb fp32 -> bf16 ----------------
__global__ __launch_bounds__(256) void conv_emb(const float4* __restrict__ in,
                                                ushort4* __restrict__ out, long n4) {
  long i = (long)blockIdx.x * 256 + threadIdx.x;
  if (i >= n4) return;
  float4 v = in[i];
  ushort4 o;
  o.x = f2bf(v.x); o.y = f2bf(v.y); o.z = f2bf(v.z); o.w = f2bf(v.w);
  out[i] = o;
}

// ------- transpose+convert W[E,U] fp32 -> Wt[U,E] bf16, 3 mats concat -------
__global__ __launch_bounds__(256) void conv_wt(const float* __restrict__ Wf,
                                               const float* __restrict__ Wi,
                                               const float* __restrict__ Wh,
                                               u16* __restrict__ wtB) {
  __shared__ float t[32][33];
  const float* W = (blockIdx.z == 0) ? Wf : ((blockIdx.z == 1) ? Wi : Wh);
  int bx = blockIdx.x * 32;  // n (input col)
  int by = blockIdx.y * 32;  // k (input row)
  int tx = threadIdx.x, ty = threadIdx.y;
  for (int j = 0; j < 32; j += 8)
    t[ty + j][tx] = W[(size_t)(by + ty + j) * UDIM + bx + tx];
  __syncthreads();
  u16* out = wtB + (size_t)blockIdx.z * UDIM * EDIM;
  for (int j = 0; j < 32; j += 8)
    out[(size_t)(bx + ty + j) * EDIM + by + tx] = f2bf(t[tx][ty + j]);
}

// ---- per-VOCAB-row gate table: 3-gate GEMM + gate nonlinearity epilogue ----
// M = 32000 = 250 m-tiles of 128 emb rows (sequential, no gather);
// n-tile = 64 u-cols x 3 gates = 192 B-rows. Wave w owns u-cols u0+w*16+fr
// for all 128 rows: acc[mt=0..7][gate=0..2]. Epilogue computes
// fn = sf/(sf+si), g = si/(sf+si)*h~ and stores f16 tables via LDS restage
// (As/Bs are dead after the K loop) for 128B-contiguous coalesced writes.
// launch_bounds(256,3): acc tile is 96 regs/lane; (256,4)'s 128-VGPR cap
// spills the accumulators (prior session R3). 3 blocks/CU is the ceiling.
__global__ __launch_bounds__(256, 3) void gate_gemm(
    const u16* __restrict__ embB, const u16* __restrict__ wtB,
    const float* __restrict__ bfp, const float* __restrict__ bip,
    const float* __restrict__ bhp,
    u16* __restrict__ FnT, u16* __restrict__ GT) {
  __shared__ __align__(16) u16 As[128 * 64];  // 16 KB
  __shared__ __align__(16) u16 Bs[192 * 64];  // 24 KB

  const int tid = threadIdx.x;
  const int wave = tid >> 6;
  const int lane = tid & 63;

  // XCD map (bijective over 4000 blocks): XCD x owns utiles {2x, 2x+1};
  // within an XCD consecutive slots alternate utile at the same mtile so
  // each A-tile is reused L2-hot, and the XCD's 2 B-slices (768 KB) stay
  // L2-resident for the whole sweep.
  const int g = blockIdx.x;
  const int x = g & 7;
  const int s = g >> 3;              // 0..499
  const int mtile = s >> 1;          // 0..249
  const int utile = x * 2 + (s & 1); // 0..15
  const int m0 = mtile * 128;
  const int u0 = utile * 64;

  // staging maps, XOR-swizzled at 16B-chunk granularity: slot (row r, chunk c)
  // holds global chunk c^(r&7) -> conflict-free ds_read_b128 on the read side.
  const u16* gA[4]; int loA[4];
  const u16* gB[6]; int loB[6];
#pragma unroll
  for (int j = 0; j < 4; ++j) {
    int idx = j * 256 + tid;
    int r = idx >> 3;
    int cg = (idx & 7) ^ (r & 7);
    gA[j] = embB + (size_t)(m0 + r) * EDIM + cg * 8;  // sequential rows now
    loA[j] = idx * 8;
  }
#pragma unroll
  for (int j = 0; j < 6; ++j) {
    int idx = j * 256 + tid;
    int r = idx >> 3;                            // 0..191
    int gr = (r >> 6) * UDIM + u0 + (r & 63);    // gate*1024 + u
    int cg = (idx & 7) ^ (r & 7);
    gB[j] = wtB + (size_t)gr * EDIM + cg * 8;
    loB[j] = idx * 8;
  }

  floatx4 acc[8][3] = {};
  const int fr = lane & 15;
  const int fq = lane >> 4;
  const int fr7 = fr & 7;
  const int un = wave * 16 + fr;  // u-col within block's 64

  for (int k0 = 0; k0 < EDIM; k0 += 64) {
#pragma unroll
    for (int j = 0; j < 4; ++j) async16(gA[j] + k0, &As[loA[j]]);
#pragma unroll
    for (int j = 0; j < 6; ++j) async16(gB[j] + k0, &Bs[loB[j]]);
    __syncthreads();
#pragma unroll
    for (int kk = 0; kk < 2; ++kk) {
      const int swz = ((kk * 4 + fq) ^ fr7) * 8;
      short8 b0 = *(const short8*)&Bs[(0 * 64 + un) * 64 + swz];
      short8 b1 = *(const short8*)&Bs[(1 * 64 + un) * 64 + swz];
      short8 b2 = *(const short8*)&Bs[(2 * 64 + un) * 64 + swz];
#pragma unroll
      for (int mt = 0; mt < 8; ++mt) {
        short8 am = *(const short8*)&As[(mt * 16 + fr) * 64 + swz];
        acc[mt][0] = __builtin_amdgcn_mfma_f32_16x16x32_bf16(am, b0, acc[mt][0], 0, 0, 0);
        acc[mt][1] = __builtin_amdgcn_mfma_f32_16x16x32_bf16(am, b1, acc[mt][1], 0, 0, 0);
        acc[mt][2] = __builtin_amdgcn_mfma_f32_16x16x32_bf16(am, b2, acc[mt][2], 0, 0, 0);
      }
    }
    __syncthreads();
  }

  // ---- epilogue: gate nonlinearity -> f16, restage in LDS, coalesced store --
  // C/D layout: col=lane&15 (u), row=(lane>>4)*4+reg. row_in_tile = mt*16+fq*4+r.
  const int ug = u0 + un;
  const float bfv = bfp[ug], biv = bip[ug], bhv = bhp[ug];
  u16* outF = As;  // 128*64 u16 = 16 KB, As/Bs dead after K loop
  u16* outG = Bs;
#pragma unroll
  for (int mt = 0; mt < 8; ++mt) {
#pragma unroll
    for (int r = 0; r < 4; ++r) {
      float fs = sigm(acc[mt][0][r] + bfv);
      float is = sigm(acc[mt][1][r] + biv);
      float hv = acc[mt][2][r] + bhv;
      float inv = __builtin_amdgcn_rcpf(fs + is);
      float fn = fs * inv;
      float gv = is * inv * hv;
      int row = mt * 16 + fq * 4 + r;
      outF[row * 64 + un] = __builtin_bit_cast(u16, (_Float16)fn);
      outG[row * 64 + un] = __builtin_bit_cast(u16, (_Float16)gv);
    }
  }
  __syncthreads();
  // 128 rows x 64 u16 per table = 1024 16B chunks; 4 per thread, row-contiguous
#pragma unroll
  for (int j = 0; j < 4; ++j) {
    int idx = j * 256 + tid;
    int row = idx >> 3, cc = idx & 7;
    size_t gb = (size_t)(m0 + row) * UDIM + u0 + cc * 8;
    *(ushort8*)&FnT[gb] = *(const ushort8*)&outF[idx * 8];
    *(ushort8*)&GT[gb] = *(const ushort8*)&outG[idx * 8];
  }
}

// ---- gather precomputed (fn, g) per token + 64-step chunk scan ----
// block = (b, chunk c): 256 threads x 4 u-cols, serial over 64 timesteps.
// Memory-bound: 2 x 8B f16 loads per (t, thread); compute is 8 FMA.
// 1024 blocks -> 16 waves/CU for HBM latency hiding.
__global__ __launch_bounds__(256) void scan_gather(
    const int* __restrict__ sent, const u16* __restrict__ FnT,
    const u16* __restrict__ GT, float* __restrict__ Fc, float* __restrict__ Gc) {
  const int b = blockIdx.x >> 4;
  const int c = blockIdx.x & (NC - 1);
  const int tid = threadIdx.x;
  __shared__ int toks[CT];
  if (tid < CT) toks[tid] = sent[b * S_LEN + c * CT + tid];
  __syncthreads();
  const int uo = tid * 4;
  floatx4 F = {1.f, 1.f, 1.f, 1.f};
  floatx4 G = {0.f, 0.f, 0.f, 0.f};
#pragma unroll 8
  for (int t = 0; t < CT; ++t) {
    const size_t ro = (size_t)toks[t] * UDIM + uo;
    ushort4 fraw = *(const ushort4*)&FnT[ro];
    ushort4 graw = *(const ushort4*)&GT[ro];
    half4 fh = __builtin_bit_cast(half4, fraw);
    half4 gh = __builtin_bit_cast(half4, graw);
    floatx4 fn = {(float)fh.x, (float)fh.y, (float)fh.z, (float)fh.w};
    floatx4 gv = {(float)gh.x, (float)gh.y, (float)gh.z, (float)gh.w};
    G = fn * G + gv;   // h' = fn*h + g composed left-to-right
    F = F * fn;
  }
  const size_t o = (size_t)c * (BATCH * UDIM) + (size_t)b * UDIM + uo;
  *(floatx4*)&Fc[o] = F;
  *(floatx4*)&Gc[o] = G;
}

// ---------------- combine chunks + MLP head ----------------
__global__ __launch_bounds__(256) void mlp_head(
    const float* __restrict__ Fc, const float* __restrict__ Gc,
    const float* __restrict__ W1, const float* __restrict__ b1,
    const float* __restrict__ W2, const float* __restrict__ b2,
    float* __restrict__ out) {
  const int b = blockIdx.x;
  const int tid = threadIdx.x;
  __shared__ float h_s[UDIM];
  __shared__ float z1[64];
  for (int u = tid; u < UDIM; u += 256) {
    float h = 0.f;
#pragma unroll
    for (int c = 0; c < NC; ++c) {
      float F = Fc[c * (BATCH * UDIM) + b * UDIM + u];
      float G = Gc[c * (BATCH * UDIM) + b * UDIM + u];
      h = F * h + G;
    }
    h_s[u] = h;
  }
  __syncthreads();
  const int j = tid >> 2, p = tid & 3;
  float partial = 0.f;
  for (int u = p * 256; u < p * 256 + 256; ++u) partial += h_s[u] * W1[u * 64 + j];
  partial += __shfl_down(partial, 1);
  partial += __shfl_down(partial, 2);
  if (p == 0) z1[j] = partial + b1[j];
  __syncthreads();
  if (tid < 64) {
    float v = z1[tid] * W2[tid];
#pragma unroll
    for (int off = 32; off > 0; off >>= 1) v += __shfl_down(v, off);
    if (tid == 0) out[b] = 1.f / (1.f + __expf(-(v + b2[0])));
  }
}

extern "C" void kernel_launch(void* const* d_in, const int* in_sizes, int n_in,
                              void* d_out, int out_size, void* d_ws, size_t ws_size,
                              hipStream_t stream) {
  const int* sent = (const int*)d_in[0];
  const float* emb = (const float*)d_in[1];
  const float* Wf = (const float*)d_in[2];
  const float* bf_ = (const float*)d_in[3];
  const float* Wi = (const float*)d_in[4];
  const float* bi_ = (const float*)d_in[5];
  const float* Wh = (const float*)d_in[6];
  const float* bh_ = (const float*)d_in[7];
  const float* W1 = (const float*)d_in[8];
  const float* b1 = (const float*)d_in[9];
  const float* W2 = (const float*)d_in[10];
  const float* b2 = (const float*)d_in[11];
  float* out = (float*)d_out;

  // workspace layout (~202 MiB)
  char* ws = (char*)d_ws;
  u16* embB = (u16*)ws;   ws += (size_t)VOCAB * EDIM * 2;       // 65,536,000
  u16* wtB = (u16*)ws;    ws += (size_t)NTOT * EDIM * 2;        //  6,291,456
  u16* FnT = (u16*)ws;    ws += (size_t)VOCAB * UDIM * 2;       // 65,536,000
  u16* GT = (u16*)ws;     ws += (size_t)VOCAB * UDIM * 2;       // 65,536,000
  float* Fc = (float*)ws; ws += (size_t)NC * BATCH * UDIM * 4;  //  4,194,304
  float* Gc = (float*)ws; ws += (size_t)NC * BATCH * UDIM * 4;  //  4,194,304

  long n4 = (long)VOCAB * EDIM / 4;
  hipLaunchKernelGGL(conv_emb, dim3((unsigned)(n4 / 256)), dim3(256), 0, stream,
                     (const float4*)emb, (ushort4*)embB, n4);
  hipLaunchKernelGGL(conv_wt, dim3(32, 32, 3), dim3(32, 8), 0, stream, Wf, Wi, Wh, wtB);
  hipLaunchKernelGGL(gate_gemm, dim3((VOCAB / 128) * (NTOT / 192)), dim3(256), 0, stream,
                     embB, wtB, bf_, bi_, bh_, FnT, GT);
  hipLaunchKernelGGL(scan_gather, dim3(BATCH * NC), dim3(256), 0, stream,
                     sent, FnT, GT, Fc, Gc);
  hipLaunchKernelGGL(mlp_head, dim3(BATCH), dim3(256), 0, stream, Fc, Gc, W1, b1, W2, b2, out);
}